// Round 5
// baseline (8451.773 us; speedup 1.0000x reference)
//
#include <hip/hip_runtime.h>
#include <math.h>

#define DD 512     // feature dim
#define NCH 64     // row chunks for column pass
#define BT 64      // gemm tile
#define KC 16      // gemm k-chunk

struct Scal {
    unsigned maxbits, minbits;  // d2 max/min as ordered uint (d2 > 0 always)
    float mid, sc;              // s2 = (mid - d2) * sc  (log2 units of M0)
    double log2T;               // log2(sum(M0))
};

// online log-sum-exp update in log2 domain: state (m, S) means sum = 2^m * S
__device__ __forceinline__ void onlineLSE(float& m, float& S, float t) {
    if (t <= m) {
        S += exp2f(t - m);
    } else {
        S = S * exp2f(m - t) + 1.0f;   // m=-inf -> exp2f(-inf)=0, S=1
        m = t;
    }
}

__device__ __forceinline__ void blockReduceMS(float& m, float& S, float* sm, float* ss) {
    int tid = threadIdx.x;
    sm[tid] = m; ss[tid] = S;
    __syncthreads();
    for (int s = 128; s > 0; s >>= 1) {
        if (tid < s) {
            float m2 = sm[tid + s], S2 = ss[tid + s];
            float m1 = sm[tid],     S1 = ss[tid];
            float nm = fmaxf(m1, m2);
            float nS;
            if (nm == -INFINITY) nS = 0.f;
            else nS = S1 * exp2f(m1 - nm) + S2 * exp2f(m2 - nm);
            sm[tid] = nm; ss[tid] = nS;
        }
        __syncthreads();
    }
    m = sm[0]; S = ss[0];
}

__global__ void k_init(Scal* s) {
    s->maxbits = 0u;
    s->minbits = 0xFFFFFFFFu;
}

__global__ void k_norms(const float* __restrict__ x, const float* __restrict__ cb,
                        float* __restrict__ xn, float* __restrict__ cn, int B) {
    int row = blockIdx.x;
    const float* src; float* dst; int r;
    if (row < B) { src = x + (size_t)row * DD; dst = xn; r = row; }
    else         { src = cb + (size_t)(row - B) * DD; dst = cn; r = row - B; }
    const float4* s4 = (const float4*)src;
    float s = 0.f;
    for (int q = threadIdx.x; q < DD / 4; q += 64) {
        float4 v = s4[q];
        s += v.x * v.x + v.y * v.y + v.z * v.z + v.w * v.w;
    }
    #pragma unroll
    for (int off = 32; off > 0; off >>= 1) s += __shfl_down(s, off, 64);
    if (threadIdx.x == 0) dst[r] = s;
}

// d2[i][j] = (xn[i] + cn[j]) - 2 * dot(x_i, c_j), fp32 tiled GEMM; also global max/min
__global__ __launch_bounds__(256) void k_gemm_d2(
        const float* __restrict__ x, const float* __restrict__ cb,
        const float* __restrict__ xn, const float* __restrict__ cn,
        float* __restrict__ d2, Scal* __restrict__ scal, int K) {
    __shared__ float As[KC][BT + 4];
    __shared__ float Bs[KC][BT + 4];
    int tid = threadIdx.x;
    int tx = tid & 15, ty = tid >> 4;
    int i0 = blockIdx.y * BT, j0 = blockIdx.x * BT;
    int lk = tid & 15, lrow = tid >> 4;   // loader: 16 k x 16 rows, 4 row-groups
    float acc[4][4] = {};
    for (int k0 = 0; k0 < DD; k0 += KC) {
        __syncthreads();
        #pragma unroll
        for (int g = 0; g < 4; ++g) {
            As[lk][lrow + g * 16] = x [(size_t)(i0 + lrow + g * 16) * DD + k0 + lk];
            Bs[lk][lrow + g * 16] = cb[(size_t)(j0 + lrow + g * 16) * DD + k0 + lk];
        }
        __syncthreads();
        #pragma unroll
        for (int k = 0; k < KC; ++k) {
            float4 a4 = *(const float4*)&As[k][ty * 4];
            float4 b4 = *(const float4*)&Bs[k][tx * 4];
            float av[4] = {a4.x, a4.y, a4.z, a4.w};
            float bv[4] = {b4.x, b4.y, b4.z, b4.w};
            #pragma unroll
            for (int r = 0; r < 4; ++r)
                #pragma unroll
                for (int c = 0; c < 4; ++c)
                    acc[r][c] = fmaf(av[r], bv[c], acc[r][c]);
        }
    }
    float xr[4], cr[4];
    #pragma unroll
    for (int r = 0; r < 4; ++r) xr[r] = xn[i0 + ty * 4 + r];
    #pragma unroll
    for (int c = 0; c < 4; ++c) cr[c] = cn[j0 + tx * 4 + c];
    float lmax = -INFINITY, lmin = INFINITY;
    #pragma unroll
    for (int r = 0; r < 4; ++r) {
        float4 o;
        float* op = (float*)&o;
        #pragma unroll
        for (int c = 0; c < 4; ++c) {
            float v = (xr[r] + cr[c]) - 2.0f * acc[r][c];  // match ref op order
            op[c] = v;
            lmax = fmaxf(lmax, v);
            lmin = fminf(lmin, v);
        }
        *(float4*)&d2[(size_t)(i0 + ty * 4 + r) * K + j0 + tx * 4] = o;
    }
    __shared__ float red[256];
    red[tid] = lmax; __syncthreads();
    for (int s = 128; s > 0; s >>= 1) { if (tid < s) red[tid] = fmaxf(red[tid], red[tid + s]); __syncthreads(); }
    if (tid == 0) atomicMax(&scal->maxbits, __float_as_uint(red[0]));
    __syncthreads();
    red[tid] = lmin; __syncthreads();
    for (int s = 128; s > 0; s >>= 1) { if (tid < s) red[tid] = fminf(red[tid], red[tid + s]); __syncthreads(); }
    if (tid == 0) atomicMin(&scal->minbits, __float_as_uint(red[0]));
}

__global__ void k_scalars(Scal* s) {
    float maxd = __uint_as_float(s->maxbits);
    float mind = __uint_as_float(s->minbits);
    float mid = (maxd + mind) * 0.5f;
    float den = (maxd - mid) + 1e-8f;
    s->mid = mid;
    // s2 = -d2n/(eps*ln2) = (mid - d2) / (den * eps * ln2)
    s->sc = (float)(1.0 / ((double)den * 0.003 * 0.693147180559945309));
}

__global__ __launch_bounds__(256) void k_pass0_row(
        const float* __restrict__ d2, const Scal* __restrict__ scal,
        float* __restrict__ rowM, float* __restrict__ rowS, int K) {
    __shared__ float sm[256], ss[256];
    int i = blockIdx.x;
    float mid = scal->mid, sc = scal->sc;
    const float4* row = (const float4*)(d2 + (size_t)i * K);
    float m = -INFINITY, S = 0.f;
    for (int q = threadIdx.x; q < K / 4; q += 256) {
        float4 v = row[q];
        onlineLSE(m, S, (mid - v.x) * sc);
        onlineLSE(m, S, (mid - v.y) * sc);
        onlineLSE(m, S, (mid - v.z) * sc);
        onlineLSE(m, S, (mid - v.w) * sc);
    }
    blockReduceMS(m, S, sm, ss);
    if (threadIdx.x == 0) { rowM[i] = m; rowS[i] = S; }
}

__global__ void k_pass0_comb(const float* __restrict__ rowM, const float* __restrict__ rowS,
                             Scal* __restrict__ scal, int B) {
    __shared__ double sd[256];
    double acc = 0.0;
    for (int i = threadIdx.x; i < B; i += 256)
        acc += exp2((double)rowM[i]) * (double)rowS[i];
    sd[threadIdx.x] = acc; __syncthreads();
    for (int s = 128; s > 0; s >>= 1) { if (threadIdx.x < s) sd[threadIdx.x] += sd[threadIdx.x + s]; __syncthreads(); }
    if (threadIdx.x == 0) scal->log2T = log2(sd[0]);
}

__global__ void k_init_lrlc(double* __restrict__ lr2, float* __restrict__ lr2f,
                            double* __restrict__ lc2, float* __restrict__ lc2f,
                            const Scal* __restrict__ scal) {
    int i = blockIdx.x * 256 + threadIdx.x;
    double v = -scal->log2T;   // M = M0 / sum(M0)
    lr2[i] = v; lr2f[i] = (float)v;
    lc2[i] = 0.0; lc2f[i] = 0.f;
}

// row normalize: rowsum_i = 2^{lr2_i} * sum_j 2^{s2_ij + lc2_j}; M /= (rowsum+1e-8)*B
__global__ __launch_bounds__(256) void k_row_pass(
        const float* __restrict__ d2, const Scal* __restrict__ scal,
        const float* __restrict__ lc2f, double* __restrict__ lr2, float* __restrict__ lr2f,
        int K, double lg2B) {
    __shared__ float sm[256], ss[256];
    int i = blockIdx.x;
    float mid = scal->mid, sc = scal->sc;
    const float4* row = (const float4*)(d2 + (size_t)i * K);
    const float4* lc4 = (const float4*)lc2f;
    float m = -INFINITY, S = 0.f;
    for (int q = threadIdx.x; q < K / 4; q += 256) {
        float4 v = row[q];
        float4 l = lc4[q];
        onlineLSE(m, S, fmaf(mid - v.x, sc, l.x));
        onlineLSE(m, S, fmaf(mid - v.y, sc, l.y));
        onlineLSE(m, S, fmaf(mid - v.z, sc, l.z));
        onlineLSE(m, S, fmaf(mid - v.w, sc, l.w));
    }
    blockReduceMS(m, S, sm, ss);
    if (threadIdx.x == 0) {
        double lr = lr2[i];
        double rowsum = exp2(lr + (double)m) * (double)S;
        double nlr = lr - log2(rowsum + 1e-8) - lg2B;
        lr2[i] = nlr; lr2f[i] = (float)nlr;
    }
}

// column pass partials: per (chunk, col): LSE over rows of s2_ij + lr2_i
__global__ __launch_bounds__(256) void k_col_pass(
        const float* __restrict__ d2, const Scal* __restrict__ scal,
        const float* __restrict__ lr2f, float* __restrict__ colM, float* __restrict__ colS,
        int B, int K) {
    int jj = (blockIdx.x * 256 + threadIdx.x) * 2;
    int ch = blockIdx.y;
    int i0 = ch * (B / NCH), i1 = i0 + B / NCH;
    float mid = scal->mid, sc = scal->sc;
    float m0 = -INFINITY, S0 = 0.f, m1 = -INFINITY, S1 = 0.f;
    for (int i = i0; i < i1; ++i) {
        float lr = lr2f[i];
        float2 v = *(const float2*)&d2[(size_t)i * K + jj];
        onlineLSE(m0, S0, fmaf(mid - v.x, sc, lr));
        onlineLSE(m1, S1, fmaf(mid - v.y, sc, lr));
    }
    size_t o = (size_t)ch * K + jj;
    *(float2*)&colM[o] = make_float2(m0, m1);
    *(float2*)&colS[o] = make_float2(S0, S1);
}

__global__ void k_col_comb(const float* __restrict__ colM, const float* __restrict__ colS,
                           double* __restrict__ lc2, float* __restrict__ lc2f,
                           int K, double lg2K) {
    int j = blockIdx.x * 256 + threadIdx.x;
    float m = -INFINITY, S = 0.f;
    for (int ch = 0; ch < NCH; ++ch) {
        float m2 = colM[(size_t)ch * K + j], S2 = colS[(size_t)ch * K + j];
        if (m2 <= m) S += S2 * exp2f(m2 - m);
        else { S = S * exp2f(m - m2) + S2; m = m2; }
    }
    double lc = lc2[j];
    double colsum = exp2(lc + (double)m) * (double)S;
    double nlc = lc - log2(colsum + 1e-8) - lg2K;
    lc2[j] = nlc; lc2f[j] = (float)nlc;
}

// probs_ij = B * 2^{lr2_i + s2_ij + lc2_j}, written in place over d2; argmax per row
__global__ __launch_bounds__(256) void k_final(
        float* __restrict__ d2probs, const Scal* __restrict__ scal,
        const double* __restrict__ lr2, const float* __restrict__ lc2f,
        float* __restrict__ oidx, int K, float lg2B) {
    __shared__ float sv[256];
    __shared__ int sj[256];
    int i = blockIdx.x;
    float mid = scal->mid, sc = scal->sc;
    float rb = (float)lr2[i] + lg2B;
    float4* row = (float4*)(d2probs + (size_t)i * K);
    const float4* lc4 = (const float4*)lc2f;
    float bt = -INFINITY; int bj = 0;
    for (int q = threadIdx.x; q < K / 4; q += 256) {
        float4 v = row[q];
        float4 l = lc4[q];
        float t0 = fmaf(mid - v.x, sc, rb + l.x);
        float t1 = fmaf(mid - v.y, sc, rb + l.y);
        float t2 = fmaf(mid - v.z, sc, rb + l.z);
        float t3 = fmaf(mid - v.w, sc, rb + l.w);
        row[q] = make_float4(exp2f(t0), exp2f(t1), exp2f(t2), exp2f(t3));
        int j0 = q * 4;
        if (t0 > bt) { bt = t0; bj = j0; }       // strict > keeps first occurrence
        if (t1 > bt) { bt = t1; bj = j0 + 1; }
        if (t2 > bt) { bt = t2; bj = j0 + 2; }
        if (t3 > bt) { bt = t3; bj = j0 + 3; }
    }
    sv[threadIdx.x] = bt; sj[threadIdx.x] = bj;
    __syncthreads();
    for (int s = 128; s > 0; s >>= 1) {
        if (threadIdx.x < s) {
            float v2 = sv[threadIdx.x + s]; int j2 = sj[threadIdx.x + s];
            if (v2 > sv[threadIdx.x] || (v2 == sv[threadIdx.x] && j2 < sj[threadIdx.x])) {
                sv[threadIdx.x] = v2; sj[threadIdx.x] = j2;
            }
        }
        __syncthreads();
    }
    if (threadIdx.x == 0) oidx[i] = (float)sj[0];
}

__global__ __launch_bounds__(128) void k_epilogue(
        const float* __restrict__ x, const float* __restrict__ cb,
        const float* __restrict__ oidx, float* __restrict__ qh, float* __restrict__ qs,
        float* __restrict__ loss) {
    __shared__ float sw[2];
    int i = blockIdx.x;
    int idx = (int)oidx[i];
    const float4* cr  = (const float4*)(cb + (size_t)idx * DD);
    const float4* xr  = (const float4*)(x + (size_t)i * DD);
    float4* qhr = (float4*)(qh + (size_t)i * DD);
    float4* qsr = (float4*)(qs + (size_t)i * DD);
    float acc = 0.f;
    for (int q = threadIdx.x; q < DD / 4; q += 128) {
        float4 c = cr[q], xv = xr[q];
        qhr[q] = c;
        float dx = c.x - xv.x, dy = c.y - xv.y, dz = c.z - xv.z, dw = c.w - xv.w;
        qsr[q] = make_float4(dx + xv.x, dy + xv.y, dz + xv.z, dw + xv.w);
        acc += dx * dx + dy * dy + dz * dz + dw * dw;
    }
    #pragma unroll
    for (int off = 32; off > 0; off >>= 1) acc += __shfl_down(acc, off, 64);
    if ((threadIdx.x & 63) == 0) sw[threadIdx.x >> 6] = acc;
    __syncthreads();
    if (threadIdx.x == 0) loss[i] = 1.25f * ((sw[0] + sw[1]) / 512.f);
}

extern "C" void kernel_launch(void* const* d_in, const int* in_sizes, int n_in,
                              void* d_out, int out_size, void* d_ws, size_t ws_size,
                              hipStream_t stream) {
    (void)n_in; (void)out_size; (void)d_ws; (void)ws_size;
    const float* x  = (const float*)d_in[0];
    const float* cb = (const float*)d_in[1];
    int B = in_sizes[0] / DD;   // 8192
    int K = in_sizes[1] / DD;   // 8192

    float* out   = (float*)d_out;
    float* qh    = out;                           // [B*DD]
    float* qs    = qh + (size_t)B * DD;           // [B*DD]  (used as scratch until epilogue)
    float* oidx  = qs + (size_t)B * DD;           // [B]
    float* probs = oidx + B;                      // [B*K]   (holds d2 until k_final)
    float* loss  = probs + (size_t)B * K;         // [B]

    // scratch carved from the quant_soft region (written only by the last kernel)
    char* p = (char*)qs;
    double* lr2  = (double*)p; p += (size_t)B * 8;
    double* lc2  = (double*)p; p += (size_t)K * 8;
    float*  lr2f = (float*)p;  p += (size_t)B * 4;
    float*  lc2f = (float*)p;  p += (size_t)K * 4;
    float*  rowM = (float*)p;  p += (size_t)B * 4;
    float*  rowS = (float*)p;  p += (size_t)B * 4;
    float*  xn   = (float*)p;  p += (size_t)B * 4;
    float*  cn   = (float*)p;  p += (size_t)K * 4;
    float*  colM = (float*)p;  p += (size_t)NCH * K * 4;
    float*  colS = (float*)p;  p += (size_t)NCH * K * 4;
    Scal*   scal = (Scal*)p;

    double lg2B = log2((double)B), lg2K = log2((double)K);

    k_init<<<1, 1, 0, stream>>>(scal);
    k_norms<<<B + K, 64, 0, stream>>>(x, cb, xn, cn, B);
    k_gemm_d2<<<dim3(K / BT, B / BT), 256, 0, stream>>>(x, cb, xn, cn, probs, scal, K);
    k_scalars<<<1, 1, 0, stream>>>(scal);
    k_pass0_row<<<B, 256, 0, stream>>>(probs, scal, rowM, rowS, K);
    k_pass0_comb<<<1, 256, 0, stream>>>(rowM, rowS, scal, B);
    k_init_lrlc<<<B / 256, 256, 0, stream>>>(lr2, lr2f, lc2, lc2f, scal);
    for (int it = 0; it < 50; ++it) {
        k_row_pass<<<B, 256, 0, stream>>>(probs, scal, lc2f, lr2, lr2f, K, lg2B);
        k_col_pass<<<dim3(K / 512, NCH), 256, 0, stream>>>(probs, scal, lr2f, colM, colS, B, K);
        k_col_comb<<<K / 256, 256, 0, stream>>>(colM, colS, lc2, lc2f, K, lg2K);
    }
    k_final<<<B, 256, 0, stream>>>(probs, scal, lr2, lc2f, oidx, K, (float)lg2B);
    k_epilogue<<<B, 128, 0, stream>>>(x, cb, oidx, qh, qs, loss);
}